// Round 6
// baseline (247.883 us; speedup 1.0000x reference)
//
#include <hip/hip_runtime.h>
#include <hip/hip_bf16.h>
#include <math.h>

#define BATCH 8
#define TDIM 4096
#define SDIM 1024
#define CDIM 512   // AUDIO_DIM
#define DDIM 768   // SEM_DIM
#define ADIM 128   // ATTN_DIM

typedef short s8v __attribute__((ext_vector_type(8)));   // 8 bf16 (4 VGPRs)
typedef float f4v __attribute__((ext_vector_type(4)));   // 4 fp32 acc

__device__ __forceinline__ short f2bf(float f) {
    unsigned u = __float_as_uint(f);
    u += 0x7fffu + ((u >> 16) & 1u);   // RNE
    return (short)(u >> 16);
}
__device__ __forceinline__ float bf2f(short s) {
    return __uint_as_float(((unsigned)(unsigned short)s) << 16);
}
__device__ __forceinline__ f4v mfma16(s8v a, s8v b, f4v c) {
    return __builtin_amdgcn_mfma_f32_16x16x32_bf16(a, b, c, 0, 0, 0);
}
// async global->LDS, 16B per lane; LDS dest = wave-uniform base + lane*16
__device__ __forceinline__ void gl_lds16(const short* g, short* l) {
    __builtin_amdgcn_global_load_lds(
        (const __attribute__((address_space(1))) unsigned int*)g,
        (__attribute__((address_space(3))) unsigned int*)l, 16, 0, 0);
}

// ---------------------------------------------------------------------------
// prep_w: transpose weights to bf16 workspace layouts.
// WqT is an LDS IMAGE: 8 chunks of [n=128][k=64], 16-B k-granule s at slot
// s ^ (n&7) inside row n (linear global_load_lds -> swizzled tile).
// ln_w folded into WqT. Block 0 zero-inits uq/vq (filled by prep_uv next).
// ---------------------------------------------------------------------------
__global__ __launch_bounds__(256) void prep_w(
    const float* __restrict__ Wq, const float* __restrict__ Wk,
    const float* __restrict__ Wv, const float* __restrict__ Wo,
    const float* __restrict__ lnw,
    short* __restrict__ WqT, short* __restrict__ WkT,
    short* __restrict__ WvT, short* __restrict__ WoT,
    float* __restrict__ uq)
{
    int gid = blockIdx.x * 256 + threadIdx.x;
    if (blockIdx.x == 0) uq[threadIdx.x] = 0.f;   // zero uq[128]+vq[128]
    {
        int k = gid >> 7, n = gid & 127;        // Wq: 512*128, fold ln_w
        int idx = (k >> 6) * 8192 + n * 64 + ((((k >> 3) & 7) ^ (n & 7)) * 8) + (k & 7);
        WqT[idx] = f2bf(Wq[gid] * lnw[k]);
    }
    #pragma unroll
    for (int i = 0; i < 2; ++i) {               // Wk/Wv: 768*128
        int e = gid + i * 65536;
        if (e < 98304) {
            int k = e >> 7, n = e & 127;
            WkT[n * 768 + k] = f2bf(Wk[e]);
            WvT[n * 768 + k] = f2bf(Wv[e]);
        }
    }
    {
        int k = gid >> 9, c = gid & 511;        // Wo: 128*512
        WoT[c * 128 + k] = f2bf(Wo[gid]);
    }
}

// ---------------------------------------------------------------------------
// prep_uv: u[a] = sum_c bf16(w[c]*Wq[c,a]); v[a] = sum_c lnb[c]*Wq[c,a].
// ---------------------------------------------------------------------------
__global__ __launch_bounds__(256) void prep_uv(
    const float* __restrict__ Wq, const float* __restrict__ lnw,
    const float* __restrict__ lnb,
    float* __restrict__ uq, float* __restrict__ vq)
{
    __shared__ float r1[128], r2[128];
    const int a = threadIdx.x & 127, h = threadIdx.x >> 7;
    const int c = blockIdx.x * 2 + h;
    float wv = Wq[c * 128 + a];
    float s1 = bf2f(f2bf(lnw[c] * wv));
    float s2 = lnb[c] * wv;
    if (h) { r1[a] = s1; r2[a] = s2; }
    __syncthreads();
    if (!h) {
        atomicAdd(&uq[a], s1 + r1[a]);
        atomicAdd(&vq[a], s2 + r2[a]);
    }
}

// ---------------------------------------------------------------------------
// xpose: x [b][c][t] fp32 (strided rows) -> xT [b][t][c] bf16, SEQUENTIAL
// reads. Grid = b(8) x cc(8 chunks of 64 c) x te(8 ranges of 512 t) = 512
// blocks x 512 thr. Per 64-t tile: in-wave 8x8 shfl transpose (lane bits
// 3..5 <-> reg bits), fp32 per-t stats partials (written to pstat[b][cc][t]),
// bf16 pack, LDS image tile [64tw][64c] with granule slot = wave ^ (t&7)
// (matches ln_q's read swizzle), then contiguous 128-B full-line copy-out.
// ---------------------------------------------------------------------------
__global__ __launch_bounds__(512, 2) void xpose(
    const float* __restrict__ x, short* __restrict__ xT,
    float* __restrict__ pstat)
{
    __shared__ __align__(16) short tile[2][64 * 64];   // 8 KB x2
    __shared__ float sred[2][8][64][2];                // 4 KB x2
    const int tid = threadIdx.x, lane = tid & 63, wave = tid >> 6;
    const int c3 = lane >> 3, tg = lane & 7;
    const int te = blockIdx.x & 7;
    const int cc = (blockIdx.x >> 3) & 7;
    const int b  = blockIdx.x >> 6;
    const int c  = cc * 64 + wave * 8 + c3;            // this lane's source row
    const float* xrow = x + ((size_t)b * CDIM + c) * TDIM + te * 512 + tg * 8;
    short* xTb = xT + ((size_t)b * TDIM + te * 512) * CDIM + cc * 64;
    float* pst = pstat + ((size_t)(b * 8 + cc) * TDIM + te * 512) * 2;

    float4 xa = *(const float4*)(xrow);
    float4 xb4 = *(const float4*)(xrow + 4);
    for (int it = 0; it < 8; ++it) {
        const int buf = it & 1;
        float w[8] = {xa.x, xa.y, xa.z, xa.w, xb4.x, xb4.y, xb4.z, xb4.w};
        if (it < 7) {   // prefetch next tile (sequential along the rows)
            xa  = *(const float4*)(xrow + (it + 1) * 64);
            xb4 = *(const float4*)(xrow + (it + 1) * 64 + 4);
        }
        // in-wave 8x8 transpose: exchange lane-bit (3+s) with reg-bit s
        #pragma unroll
        for (int s = 0; s < 3; ++s) {
            const int mlane = 8 << s, rb = 1 << s;
            const bool up = (lane & mlane) != 0;
            #pragma unroll
            for (int i = 0; i < 8; ++i) {
                if (i & rb) continue;
                float lo = w[i], hi = w[i | rb];
                float send = up ? lo : hi;
                float got = __shfl_xor(send, mlane);
                w[i]      = up ? got : lo;
                w[i | rb] = up ? hi  : got;
            }
        }
        // now: reg j = x[cc*64 + wave*8 + j][tl = tg*8 + c3] (fp32)
        const int tl = tg * 8 + c3;
        float s1 = 0.f, s2 = 0.f;
        #pragma unroll
        for (int j = 0; j < 8; ++j) { s1 += w[j]; s2 += w[j] * w[j]; }
        sred[buf][wave][tl][0] = s1;
        sred[buf][wave][tl][1] = s2;
        s8v pk;
        #pragma unroll
        for (int j = 0; j < 8; ++j) pk[j] = f2bf(w[j]);
        // granule (= wave) stored at slot wave ^ (tl&7); tl&7 == c3
        *(s8v*)&tile[buf][tl * 64 + ((wave ^ c3) * 8)] = pk;
        __syncthreads();
        {   // copy out: 8 rows x full 128-B lines per wave, 1-KB row stride
            const int row = tid >> 3, part = tid & 7;
            *(s8v*)&xTb[(size_t)(it * 64 + row) * CDIM + part * 8] =
                *(const s8v*)&tile[buf][row * 64 + part * 8];
        }
        if (tid < 128) {   // reduce 8 wave-partials -> pstat
            const int t_l = tid >> 1, wh = tid & 1;
            float s = 0.f;
            #pragma unroll
            for (int ww = 0; ww < 8; ++ww) s += sred[buf][ww][t_l][wh];
            pst[(it * 64 + t_l) * 2 + wh] = s;
        }
    }
}

// ---------------------------------------------------------------------------
// ln_q v7: consumes the sequential pre-swizzled xT image. 256 blocks
// (b x 32 t-tiles of 128) x 512 thr, 8 waves x 16 t-rows x 128 cols, acc[8].
// Both A (xT) and B (Wq image) staged via gl_lds16 with linear dest, dbuf,
// one barrier per 64-c chunk. LN stats pre-reduced from pstat. Epilogue:
// Q = (rs*(S - mu*u) + v + bq) * scale.  LDS 65 KB -> 2 blocks/CU.
// ---------------------------------------------------------------------------
__global__ __launch_bounds__(512, 2) void ln_q(
    const short* __restrict__ xT, const short* __restrict__ WqI,
    const float* __restrict__ pstat, const float* __restrict__ uq,
    const float* __restrict__ vq, const float* __restrict__ bq,
    short* __restrict__ Qb)
{
    __shared__ __align__(16) short sA[2][128 * 64];  // xT chunk image, 16 KB x2
    __shared__ __align__(16) short sW[2][64 * 128];  // Wq chunk image, 16 KB x2
    __shared__ float sLN[128][2];
    const int tid = threadIdx.x, lane = tid & 63, wave = tid >> 6;
    const int ln15 = lane & 15, q = lane >> 4, kq = q * 8;
    const int b = blockIdx.x >> 5;
    const int t0 = (blockIdx.x & 31) * 128;
    const short* xTb = xT + ((size_t)b * TDIM + t0) * CDIM;

    if (tid < 256) {   // stage LN stats: sum the 8 c-chunk partials per t
        const int t_l = tid >> 1, wh = tid & 1;
        float s = 0.f;
        #pragma unroll
        for (int cc = 0; cc < 8; ++cc)
            s += pstat[((size_t)(b * 8 + cc) * TDIM + t0 + t_l) * 2 + wh];
        sLN[t_l][wh] = s;
    }

    const int m = wave * 16 + ln15;
    f4v acc[8];
    #pragma unroll
    for (int j = 0; j < 8; ++j) acc[j] = (f4v)0.0f;

#define STAGE(BUF, CC) do {                                                   \
    _Pragma("unroll")                                                         \
    for (int ii = 0; ii < 2; ++ii) {                                          \
        int r0 = (wave * 2 + ii) * 8;                                         \
        gl_lds16(&xTb[(size_t)(r0 + (lane >> 3)) * CDIM + (CC) * 64 + (lane & 7) * 8], \
                 &sA[BUF][r0 * 64]);                                          \
        int gi = ii * 512 + wave * 64;                                        \
        gl_lds16(&WqI[(size_t)(CC) * 8192 + (size_t)(gi + lane) * 8],         \
                 &sW[BUF][gi * 8]);                                           \
    }                                                                         \
} while (0)

    STAGE(0, 0);
    __syncthreads();
    for (int cc = 0; cc < 8; ++cc) {
        const int cur = cc & 1;
        if (cc < 7) STAGE(cur ^ 1, cc + 1);
        #pragma unroll
        for (int kk = 0; kk < 2; ++kk) {
            s8v a = *(const s8v*)&sA[cur][m * 64 + (((kk * 4 + q) ^ (m & 7)) * 8)];
            #pragma unroll
            for (int j = 0; j < 8; ++j) {
                int n = j * 16 + ln15;
                s8v bb = *(const s8v*)&sW[cur][n * 64 + (((kk * 4 + q) ^ (n & 7)) * 8)];
                acc[j] = mfma16(a, bb, acc[j]);
            }
        }
        __syncthreads();
    }
#undef STAGE

    float u4[8], v4[8];
    #pragma unroll
    for (int j = 0; j < 8; ++j) {
        int col = j * 16 + ln15;
        u4[j] = uq[col]; v4[j] = vq[col] + bq[col];
    }
    const float scale = 0.08838834764831845f;  // 1/sqrt(128)
    #pragma unroll
    for (int r = 0; r < 4; ++r) {
        const int t_l = wave * 16 + q * 4 + r;
        float s1 = sLN[t_l][0], s2 = sLN[t_l][1];
        float mu = s1 * (1.f / 512.f);
        float var = s2 * (1.f / 512.f) - mu * mu;
        float rs = rsqrtf(var + 1e-5f);
        #pragma unroll
        for (int j = 0; j < 8; ++j) {
            float qv = (rs * (acc[j][r] - mu * u4[j]) + v4[j]) * scale;
            Qb[((size_t)b * TDIM + t0 + t_l) * ADIM + (j * 16 + ln15)] = f2bf(qv);
        }
    }
}

// ---------------------------------------------------------------------------
// kv_proj: K = sem @ Wk + bk -> Kb [b][s][a];  V -> Vb [b][a][s] (transposed)
// ---------------------------------------------------------------------------
__global__ __launch_bounds__(256) void kv_proj(
    const float* __restrict__ sem,
    const short* __restrict__ WkT, const float* __restrict__ bk,
    const short* __restrict__ WvT, const float* __restrict__ bv,
    short* __restrict__ Kb, short* __restrict__ Vb)
{
    __shared__ __align__(16) short sA[32 * 40];      // [row][k32 + pad8]
    __shared__ __align__(16) short sW[2][128 * 40];  // [K/V][n][k32 + pad8]
    const int tid = threadIdx.x, lane = tid & 63, wave = tid >> 6;
    const int ln15 = lane & 15, q = lane >> 4, kq = q * 8;
    const int r0 = blockIdx.x * 32;
    const int b = r0 >> 10, sbase = r0 & 1023;
    const int kv = wave >> 1;        // 0 = K, 1 = V
    const int mh = wave & 1;
    const int m  = mh * 16 + ln15;

    f4v acc[8];
    #pragma unroll
    for (int j = 0; j < 8; ++j) acc[j] = (f4v)0.0f;

    const int srow = tid >> 3;          // 0..31
    const int sk4  = (tid & 7) * 4;     // 0,4,..,28

    for (int kc = 0; kc < DDIM / 32; ++kc) {
        __syncthreads();
        {   // stage sem tile [32][32] fp32 -> bf16 (uint2 = 4 bf16)
            float4 f = *(const float4*)&sem[(size_t)(r0 + srow) * DDIM + kc * 32 + sk4];
            uint2 pk;
            pk.x = (unsigned short)f2bf(f.x) | ((unsigned)(unsigned short)f2bf(f.y) << 16);
            pk.y = (unsigned short)f2bf(f.z) | ((unsigned)(unsigned short)f2bf(f.w) << 16);
            *(uint2*)&sA[srow * 40 + sk4] = pk;
        }
        #pragma unroll
        for (int i = 0; i < 2; ++i) {   // stage Wk/Wv chunks [128][32]
            int idx8 = i * 256 + tid;
            int n = idx8 >> 2, k8 = (idx8 & 3) * 8;
            *(s8v*)&sW[0][n * 40 + k8] = *(const s8v*)&WkT[(size_t)n * 768 + kc * 32 + k8];
            *(s8v*)&sW[1][n * 40 + k8] = *(const s8v*)&WvT[(size_t)n * 768 + kc * 32 + k8];
        }
        __syncthreads();
        s8v a = *(const s8v*)&sA[m * 40 + kq];
        #pragma unroll
        for (int j = 0; j < 8; ++j) {
            s8v bb = *(const s8v*)&sW[kv][(j * 16 + ln15) * 40 + kq];
            acc[j] = mfma16(a, bb, acc[j]);
        }
    }
    const int s_in_b = sbase + mh * 16 + q * 4;
    if (kv == 0) {
        #pragma unroll
        for (int j = 0; j < 8; ++j) {
            int col = j * 16 + ln15;
            float bias = bk[col];
            #pragma unroll
            for (int r = 0; r < 4; ++r)
                Kb[((size_t)b * SDIM + s_in_b + r) * ADIM + col] = f2bf(acc[j][r] + bias);
        }
    } else {
        #pragma unroll
        for (int j = 0; j < 8; ++j) {
            int col = j * 16 + ln15;
            float bias = bv[col];
            uint2 pk;
            pk.x = (unsigned short)f2bf(acc[j][0] + bias) | ((unsigned)(unsigned short)f2bf(acc[j][1] + bias) << 16);
            pk.y = (unsigned short)f2bf(acc[j][2] + bias) | ((unsigned)(unsigned short)f2bf(acc[j][3] + bias) << 16);
            *(uint2*)&Vb[((size_t)b * ADIM + col) * SDIM + s_in_b] = pk;
        }
    }
}

// ---------------------------------------------------------------------------
// attn: flash-style, no max subtraction. Q frags in registers (no sQ).
// XOR-swizzled unpadded LDS tiles; double-buffered K/V with register
// prefetch; row-sums via MFMA-with-ones. 512 blocks, 2/CU, LDS 72 KB.
// ---------------------------------------------------------------------------
__global__ __launch_bounds__(256) void attn(
    const short* __restrict__ Qb, const short* __restrict__ Kb,
    const short* __restrict__ Vb, short* __restrict__ Cx)
{
    __shared__ __align__(16) short sK [2][64 * 128];  // [s][a]  kb ^= row&15
    __shared__ __align__(16) short sVT[2][128 * 64];  // [a][s]  kb ^= row&7
    __shared__ __align__(16) short sP [64 * 64];      // [t][s]  kb ^= row&7 (wave-private rows)
    const int tid = threadIdx.x, lane = tid & 63, wave = tid >> 6;
    const int ln15 = lane & 15, q = lane >> 4, kq = q * 8;
    const int b = blockIdx.x >> 6;
    const int t0 = (blockIdx.x & 63) * 64;
    const int m = wave * 16 + ln15;

    const int krow = tid >> 4, kkb = tid & 15;   // K staging: row = i*16+krow
    const int varow = tid >> 3, vkb = tid & 7;   // VT staging: row = i*32+varow

    s8v qf[4];
    {
        const short* qp = Qb + ((size_t)b * TDIM + t0 + m) * ADIM + kq;
        #pragma unroll
        for (int kc = 0; kc < 4; ++kc) qf[kc] = *(const s8v*)(qp + kc * 32);
    }
    s8v ones;
    #pragma unroll
    for (int j = 0; j < 8; ++j) ones[j] = (short)0x3F80;  // bf16 1.0

    f4v accO[8]; f4v accL = (f4v)0.0f;
    #pragma unroll
    for (int j = 0; j < 8; ++j) accO[j] = (f4v)0.0f;

    const short* Kbase = Kb + (size_t)b * SDIM * ADIM;
    const short* Vbase = Vb + (size_t)b * ADIM * SDIM;
    s8v rk[4], rv[4];

    #pragma unroll
    for (int i = 0; i < 4; ++i) {       // prologue: load + store chunk 0
        rk[i] = *(const s8v*)(Kbase + (size_t)(i * 16 + krow) * ADIM + kkb * 8);
        rv[i] = *(const s8v*)(Vbase + (size_t)(i * 32 + varow) * SDIM + vkb * 8);
    }
    #pragma unroll
    for (int i = 0; i < 4; ++i) {
        int r = i * 16 + krow;
        *(s8v*)&sK[0][r * 128 + ((kkb ^ (r & 15)) * 8)] = rk[i];
        int a = i * 32 + varow;
        *(s8v*)&sVT[0][a * 64 + ((vkb ^ (a & 7)) * 8)] = rv[i];
    }
    __syncthreads();

    for (int sc = 0; sc < SDIM / 64; ++sc) {
        const int cur = sc & 1;
        if (sc < 15) {                  // prefetch next chunk into registers
            const int s0n = (sc + 1) * 64;
            #pragma unroll
            for (int i = 0; i < 4; ++i) {
                rk[i] = *(const s8v*)(Kbase + (size_t)(s0n + i * 16 + krow) * ADIM + kkb * 8);
                rv[i] = *(const s8v*)(Vbase + (size_t)(i * 32 + varow) * SDIM + s0n + vkb * 8);
            }
        }
        // QK^T -> exp -> sP (wave-private rows, no block barrier needed)
        #pragma unroll
        for (int j = 0; j < 4; ++j) {
            f4v sacc = (f4v)0.0f;
            const int row = j * 16 + ln15;
            #pragma unroll
            for (int kc = 0; kc < 4; ++kc) {
                s8v bb = *(const s8v*)&sK[cur][row * 128 + (((kc * 4 + q) ^ (row & 15)) * 8)];
                sacc = mfma16(qf[kc], bb, sacc);
            }
            #pragma unroll
            for (int r = 0; r < 4; ++r) {
                float ev = __expf(sacc[r]);
                int prow = wave * 16 + q * 4 + r;
                int pcol = j * 16 + ln15;
                sP[prow * 64 + (((pcol >> 3) ^ (prow & 7)) * 8) + (pcol & 7)] = f2bf(ev);
            }
        }
        // PV + row-sum via MFMA-with-ones
        #pragma unroll
        for (int kc = 0; kc < 2; ++kc) {
            s8v pa = *(const s8v*)&sP[m * 64 + (((kc * 4 + q) ^ (m & 7)) * 8)];
            accL = mfma16(pa, ones, accL);
            #pragma unroll
            for (int j = 0; j < 8; ++j) {
                int a = j * 16 + ln15;
                s8v bb = *(const s8v*)&sVT[cur][a * 64 + (((kc * 4 + q) ^ (a & 7)) * 8)];
                accO[j] = mfma16(pa, bb, accO[j]);
            }
        }
        if (sc < 15) {                  // write prefetched chunk to other buffer
            #pragma unroll
            for (int i = 0; i < 4; ++i) {
                int r = i * 16 + krow;
                *(s8v*)&sK[cur ^ 1][r * 128 + ((kkb ^ (r & 15)) * 8)] = rk[i];
                int a = i * 32 + varow;
                *(s8v*)&sVT[cur ^ 1][a * 64 + ((vkb ^ (a & 7)) * 8)] = rv[i];
            }
        }
        __syncthreads();
    }
    #pragma unroll
    for (int r = 0; r < 4; ++r) {
        float rinv = 1.0f / accL[r];
        int t = t0 + wave * 16 + q * 4 + r;
        #pragma unroll
        for (int j = 0; j < 8; ++j) {
            int col = j * 16 + ln15;
            Cx[((size_t)b * TDIM + t) * ADIM + col] = f2bf(accO[j][r] * rinv);
        }
    }
}

// ---------------------------------------------------------------------------
// out_proj: delta = ctx @ Wo + bo, written transposed [B][C][T] coalesced
// ---------------------------------------------------------------------------
__global__ __launch_bounds__(256) void out_proj(
    const short* __restrict__ Cx, const short* __restrict__ WoT,
    const float* __restrict__ bo, float* __restrict__ out)
{
    __shared__ __align__(16) short sCtx[64 * 136];  // [t][a128 + pad8]
    __shared__ __align__(16) char  buf[128 * 136 * 2];
    short* sWoT = (short*)buf;                      // [c128][k128 + pad8]
    float* outT = (float*)buf;                      // [c128][t64 + pad4]
    const int tid = threadIdx.x, lane = tid & 63, wave = tid >> 6;
    const int ln15 = lane & 15, q = lane >> 4, kq = q * 8;
    const int b = blockIdx.x >> 8;
    const int rem = blockIdx.x & 255;
    const int t0 = (rem & 63) * 64;
    const int c0 = (rem >> 6) * 128;

    #pragma unroll
    for (int i = 0; i < 4; ++i) {
        int idx8 = i * 256 + tid;
        int row = idx8 >> 4, a8 = (idx8 & 15) * 8;
        *(s8v*)&sCtx[row * 136 + a8] = *(const s8v*)&Cx[((size_t)b * TDIM + t0 + row) * ADIM + a8];
    }
    #pragma unroll
    for (int i = 0; i < 8; ++i) {
        int idx8 = i * 256 + tid;
        int n = idx8 >> 4, k8 = (idx8 & 15) * 8;
        *(s8v*)&sWoT[n * 136 + k8] = *(const s8v*)&WoT[(size_t)(c0 + n) * ADIM + k8];
    }
    __syncthreads();
    f4v acc[8];
    #pragma unroll
    for (int j = 0; j < 8; ++j) acc[j] = (f4v)0.0f;
    const int m = wave * 16 + ln15;
    #pragma unroll
    for (int kc = 0; kc < 4; ++kc) {
        s8v a = *(const s8v*)&sCtx[m * 136 + kc * 32 + kq];
        #pragma unroll
        for (int j = 0; j < 8; ++j) {
            s8v bb = *(const s8v*)&sWoT[(j * 16 + ln15) * 136 + kc * 32 + kq];
            acc[j] = mfma16(a, bb, acc[j]);
        }
    }
    __syncthreads();    // reuse buf as outT
    #pragma unroll
    for (int j = 0; j < 8; ++j) {
        int cl = j * 16 + ln15;
        float bias = bo[c0 + cl];
        #pragma unroll
        for (int r = 0; r < 4; ++r) {
            int tl = wave * 16 + q * 4 + r;
            outT[cl * 68 + tl] = acc[j][r] + bias;
        }
    }
    __syncthreads();
    #pragma unroll
    for (int i = 0; i < 8; ++i) {
        int idx4 = i * 256 + tid;
        int c = idx4 >> 4, t4 = (idx4 & 15) * 4;
        float4 v = *(const float4*)&outT[c * 68 + t4];
        *(float4*)&out[((size_t)b * CDIM + c0 + c) * TDIM + t0 + t4] = v;
    }
}

// ---------------------------------------------------------------------------
extern "C" void kernel_launch(void* const* d_in, const int* in_sizes, int n_in,
                              void* d_out, int out_size, void* d_ws, size_t ws_size,
                              hipStream_t stream) {
    const float* x   = (const float*)d_in[0];
    const float* sem = (const float*)d_in[1];
    const float* lnw = (const float*)d_in[2];
    const float* lnb = (const float*)d_in[3];
    const float* Wq  = (const float*)d_in[4];
    const float* bq  = (const float*)d_in[5];
    const float* Wk  = (const float*)d_in[6];
    const float* bk  = (const float*)d_in[7];
    const float* Wv  = (const float*)d_in[8];
    const float* bv  = (const float*)d_in[9];
    const float* Wo  = (const float*)d_in[10];
    const float* bo  = (const float*)d_in[11];
    float* out = (float*)d_out;

    short* ws  = (short*)d_ws;
    short* Qb  = ws;                                    // [B][T][A]  bf16
    short* Kb  = Qb  + (size_t)BATCH * TDIM * ADIM;     // [B][S][A]
    short* Vb  = Kb  + (size_t)BATCH * SDIM * ADIM;     // [B][A][S]  (transposed)
    short* Cx  = Vb  + (size_t)BATCH * SDIM * ADIM;     // [B][T][A]
    short* WqT = Cx  + (size_t)BATCH * TDIM * ADIM;     // [8][128][64] LDS image (ln_w folded)
    short* WkT = WqT + 128 * 512;                       // [128][768]
    short* WvT = WkT + 128 * 768;                       // [128][768]
    short* WoT = WvT + 128 * 768;                       // [512][128]
    float* uq  = (float*)(WoT + 512 * 128);             // [128]
    float* vq  = uq + 128;                              // [128]
    short* xTw = (short*)(vq + 128);                    // [B][T][C] bf16 image
    float* pst = (float*)(xTw + (size_t)BATCH * TDIM * CDIM);  // [B][8][T][2]

    hipLaunchKernelGGL(prep_w,  dim3(256),  dim3(256), 0, stream,
                       Wq, Wk, Wv, Wo, lnw, WqT, WkT, WvT, WoT, uq);
    hipLaunchKernelGGL(prep_uv, dim3(256),  dim3(256), 0, stream, Wq, lnw, lnb, uq, vq);
    hipLaunchKernelGGL(xpose,   dim3(512),  dim3(512), 0, stream, x, xTw, pst);
    hipLaunchKernelGGL(kv_proj, dim3(256),  dim3(256), 0, stream, sem, WkT, bk, WvT, bv, Kb, Vb);
    hipLaunchKernelGGL(ln_q,    dim3(256),  dim3(512), 0, stream, xTw, WqT, pst, uq, vq, bq, Qb);
    hipLaunchKernelGGL(attn,    dim3(512),  dim3(256), 0, stream, Qb, Kb, Vb, Cx);
    hipLaunchKernelGGL(out_proj,dim3(2048), dim3(256), 0, stream, Cx, WoT, bo, out);
}

// Round 7
// 232.947 us; speedup vs baseline: 1.0641x; 1.0641x over previous
//
#include <hip/hip_runtime.h>
#include <hip/hip_bf16.h>
#include <math.h>

#define BATCH 8
#define TDIM 4096
#define SDIM 1024
#define CDIM 512   // AUDIO_DIM
#define DDIM 768   // SEM_DIM
#define ADIM 128   // ATTN_DIM

typedef short s8v __attribute__((ext_vector_type(8)));   // 8 bf16 (4 VGPRs)
typedef float f4v __attribute__((ext_vector_type(4)));   // 4 fp32 acc

__device__ __forceinline__ short f2bf(float f) {
    unsigned u = __float_as_uint(f);
    u += 0x7fffu + ((u >> 16) & 1u);   // RNE
    return (short)(u >> 16);
}
__device__ __forceinline__ float bf2f(short s) {
    return __uint_as_float(((unsigned)(unsigned short)s) << 16);
}
__device__ __forceinline__ f4v mfma16(s8v a, s8v b, f4v c) {
    return __builtin_amdgcn_mfma_f32_16x16x32_bf16(a, b, c, 0, 0, 0);
}
// async global->LDS, 16B per lane; LDS dest = wave-uniform base + lane*16
__device__ __forceinline__ void gl_lds16(const short* g, short* l) {
    __builtin_amdgcn_global_load_lds(
        (const __attribute__((address_space(1))) unsigned int*)g,
        (__attribute__((address_space(3))) unsigned int*)l, 16, 0, 0);
}

// ---------------------------------------------------------------------------
// prep: 512 blocks x 256 thr, two roles.
// Blocks 0-255 (w-role): weight transposes. WqT is an LDS IMAGE: 8 chunks of
// [n=128][k=64], 16-B granule s at slot s ^ (n&7) in row n; ln_w folded in.
// Blocks 256-511 (uv-role): u[a] = sum_c bf16(w[c]*Wq[c,a]),
// v[a] = sum_c lnb[c]*Wq[c,a], via atomicAdd (uq/vq zeroed by memset before).
// ---------------------------------------------------------------------------
__global__ __launch_bounds__(256) void prep(
    const float* __restrict__ Wq, const float* __restrict__ Wk,
    const float* __restrict__ Wv, const float* __restrict__ Wo,
    const float* __restrict__ lnw, const float* __restrict__ lnb,
    short* __restrict__ WqT, short* __restrict__ WkT,
    short* __restrict__ WvT, short* __restrict__ WoT,
    float* __restrict__ uq, float* __restrict__ vq)
{
    __shared__ float r1[128], r2[128];
    if (blockIdx.x < 256) {
        int gid = blockIdx.x * 256 + threadIdx.x;
        {
            int k = gid >> 7, n = gid & 127;        // Wq: 512*128, fold ln_w
            int idx = (k >> 6) * 8192 + n * 64 + ((((k >> 3) & 7) ^ (n & 7)) * 8) + (k & 7);
            WqT[idx] = f2bf(Wq[gid] * lnw[k]);
        }
        #pragma unroll
        for (int i = 0; i < 2; ++i) {               // Wk/Wv: 768*128
            int e = gid + i * 65536;
            if (e < 98304) {
                int k = e >> 7, n = e & 127;
                WkT[n * 768 + k] = f2bf(Wk[e]);
                WvT[n * 768 + k] = f2bf(Wv[e]);
            }
        }
        {
            int k = gid >> 9, c = gid & 511;        // Wo: 128*512
            WoT[c * 128 + k] = f2bf(Wo[gid]);
        }
    } else {
        const int a = threadIdx.x & 127, h = threadIdx.x >> 7;
        const int c = (blockIdx.x - 256) * 2 + h;
        float wv = Wq[c * 128 + a];
        float s1 = bf2f(f2bf(lnw[c] * wv));
        float s2 = lnb[c] * wv;
        if (h) { r1[a] = s1; r2[a] = s2; }
        __syncthreads();
        if (!h) {
            atomicAdd(&uq[a], s1 + r1[a]);
            atomicAdd(&vq[a], s2 + r2[a]);
        }
    }
}

// ---------------------------------------------------------------------------
// mid: role-fused ln_q (v5, verified R4) + kv_proj (verified R0-R6).
// 768 blocks x 512 thr, role by blockIdx%3 (2:1 ln:kv interleave in dispatch
// order). ln-role blocks do strided x reads (memory-system-queue bound,
// CUs idle); kv-role blocks do MFMA/LDS work -> co-resident overlap that
// serial stream order forbids. LDS union 55.3 KB -> 2 blocks/CU.
//
// ln-role: contiguous-x streaming LN-fold. BM=64 t, 8 k-chunks of 64 c,
// dbuf, 1 barrier/chunk; gl_lds16 Wq image; shfl_xor(16) pair transpose;
// swizzle slot = (c>>3) ^ ((t>>2)&7). Q = (rs*(S - mu*u) + v + bq)*scale.
// kv-role: K = sem@Wk+bk -> Kb [b][s][a]; V -> Vb [b][a][s]. Threads
// 256-511 idle (barrier-matching only).
// ---------------------------------------------------------------------------
__global__ __launch_bounds__(512, 4) void mid(
    const float* __restrict__ x, const short* __restrict__ WqI,
    const float* __restrict__ uq, const float* __restrict__ vq,
    const float* __restrict__ bq, short* __restrict__ Qb,
    const float* __restrict__ sem,
    const short* __restrict__ WkT, const float* __restrict__ bk,
    const short* __restrict__ WvT, const float* __restrict__ bv,
    short* __restrict__ Kb, short* __restrict__ Vb)
{
    __shared__ __align__(16) char smem[55296];
    const int tid = threadIdx.x, lane = tid & 63, wave = tid >> 6;
    const int ln15 = lane & 15, q = lane >> 4, kq = q * 8;
    const int bid = blockIdx.x;

    if ((bid % 3) != 2) {
        // ================= ln_q role =================
        const int ln_id = (bid / 3) * 2 + (bid % 3);     // 0..511
        short* sXp = (short*)smem;                       // [2][64*72]
        short* sWp = (short*)(smem + 18432);             // [2][64*128]
        float* redwp = (float*)(smem + 51200);           // [8][16][4][2]
        const int b = ln_id >> 6;
        const int t0 = (ln_id & 63) * 64;
        const float* xb = x + (size_t)b * CDIM * TDIM + t0;

        const int rg = lane >> 4;            // 0..3 row-in-wave
        const int g  = rg & 1;               // c parity within pair
        const int L  = lane & 15;
        const int t4 = L * 4;                // t-quad this lane loads
        const int crow = wave * 4 + rg;      // chunk-local c row (and +32)

        float ps1[4] = {0.f,0.f,0.f,0.f}, ps2[4] = {0.f,0.f,0.f,0.f};
        const int wr = wave & 3, wc = wave >> 2;
        const int m = wr * 16 + ln15;        // output t-row (block-local)
        const int swzm = (m >> 2) & 7;
        f4v acc[4];
        #pragma unroll
        for (int j = 0; j < 4; ++j) acc[j] = (f4v)0.0f;

        float4 xv[2];

#define PROC_X(BUF) do {                                                      \
    _Pragma("unroll")                                                         \
    for (int i = 0; i < 2; ++i) {                                             \
        float4 v = xv[i];                                                     \
        ps1[0] += v.x; ps2[0] += v.x * v.x;                                   \
        ps1[1] += v.y; ps2[1] += v.y * v.y;                                   \
        ps1[2] += v.z; ps2[2] += v.z * v.z;                                   \
        ps1[3] += v.w; ps2[3] += v.w * v.w;                                   \
        float o0 = __shfl_xor(v.x, 16); float o1 = __shfl_xor(v.y, 16);       \
        float o2 = __shfl_xor(v.z, 16); float o3 = __shfl_xor(v.w, 16);       \
        const int c   = crow + i * 32;                                        \
        const int cdw = c & ~1;                                               \
        unsigned wA, wB; int tA, tB;                                          \
        if (g == 0) {                                                         \
            tA = t4; tB = t4 + 1;                                             \
            wA = (unsigned short)f2bf(v.x) | ((unsigned)(unsigned short)f2bf(o0) << 16); \
            wB = (unsigned short)f2bf(v.y) | ((unsigned)(unsigned short)f2bf(o1) << 16); \
        } else {                                                              \
            tA = t4 + 2; tB = t4 + 3;                                         \
            wA = (unsigned short)f2bf(o2) | ((unsigned)(unsigned short)f2bf(v.z) << 16); \
            wB = (unsigned short)f2bf(o3) | ((unsigned)(unsigned short)f2bf(v.w) << 16); \
        }                                                                     \
        *(unsigned*)&sXp[(BUF) * 4608 + tA * 72 + (((cdw >> 3) ^ ((tA >> 2) & 7)) * 8) + (cdw & 7)] = wA; \
        *(unsigned*)&sXp[(BUF) * 4608 + tB * 72 + (((cdw >> 3) ^ ((tB >> 2) & 7)) * 8) + (cdw & 7)] = wB; \
    }                                                                         \
} while (0)

        // ---- prologue: chunk 0
        xv[0] = *(const float4*)&xb[(size_t)crow * TDIM + t4];
        xv[1] = *(const float4*)&xb[(size_t)(crow + 32) * TDIM + t4];
        #pragma unroll
        for (int i = 0; i < 2; ++i) {
            int gi = i * 512 + wave * 64;
            gl_lds16(&WqI[(size_t)(gi + lane) * 8], &sWp[gi * 8]);
        }
        PROC_X(0);
        __syncthreads();

        // ---- main loop: 8 chunks, dbuf, one barrier per chunk
        for (int kc = 0; kc < 8; ++kc) {
            const int cur = kc & 1;
            if (kc < 7) {
                const float* xc = xb + (size_t)(kc + 1) * 64 * TDIM;
                xv[0] = *(const float4*)&xc[(size_t)crow * TDIM + t4];
                xv[1] = *(const float4*)&xc[(size_t)(crow + 32) * TDIM + t4];
                const short* wch = WqI + (size_t)(kc + 1) * 8192;
                #pragma unroll
                for (int i = 0; i < 2; ++i) {
                    int gi = i * 512 + wave * 64;
                    gl_lds16(&wch[(size_t)(gi + lane) * 8], &sWp[(cur ^ 1) * 8192 + gi * 8]);
                }
            }
            #pragma unroll
            for (int kk = 0; kk < 2; ++kk) {
                s8v a = *(const s8v*)&sXp[cur * 4608 + m * 72 + (((kk * 4 + q) ^ swzm) * 8)];
                #pragma unroll
                for (int j = 0; j < 4; ++j) {
                    int n = wc * 64 + j * 16 + ln15;
                    s8v bb = *(const s8v*)&sWp[cur * 8192 + n * 64 + (((kk * 4 + q) ^ (n & 7)) * 8)];
                    acc[j] = mfma16(a, bb, acc[j]);
                }
            }
            if (kc < 7) PROC_X(cur ^ 1);
            __syncthreads();
        }
#undef PROC_X

        // ---- stats: reduce lanes sharing t4 (xor 16, 32), park per wave
        #pragma unroll
        for (int mk = 16; mk <= 32; mk <<= 1) {
            #pragma unroll
            for (int jj = 0; jj < 4; ++jj) {
                ps1[jj] += __shfl_xor(ps1[jj], mk);
                ps2[jj] += __shfl_xor(ps2[jj], mk);
            }
        }
        if (lane < 16) {
            #pragma unroll
            for (int jj = 0; jj < 4; ++jj) {
                redwp[((wave * 16 + L) * 4 + jj) * 2 + 0] = ps1[jj];
                redwp[((wave * 16 + L) * 4 + jj) * 2 + 1] = ps2[jj];
            }
        }
        __syncthreads();

        // ---- epilogue: Q = (rs*(S - mu*u) + v + bq) * scale
        float u4[4], v4[4];
        #pragma unroll
        for (int j = 0; j < 4; ++j) {
            int col = wc * 64 + j * 16 + ln15;
            u4[j] = uq[col]; v4[j] = vq[col] + bq[col];
        }
        const float scale = 0.08838834764831845f;  // 1/sqrt(128)
        const int quad = wr * 4 + q;
        #pragma unroll
        for (int r = 0; r < 4; ++r) {
            float s1 = 0.f, s2 = 0.f;
            #pragma unroll
            for (int w = 0; w < 8; ++w) {
                float2 p = *(const float2*)&redwp[((w * 16 + quad) * 4 + r) * 2];
                s1 += p.x; s2 += p.y;
            }
            float mu = s1 * (1.f / 512.f);
            float var = s2 * (1.f / 512.f) - mu * mu;
            float rs = rsqrtf(var + 1e-5f);
            int t = t0 + wr * 16 + q * 4 + r;
            #pragma unroll
            for (int j = 0; j < 4; ++j) {
                float qv = (rs * (acc[j][r] - mu * u4[j]) + v4[j]) * scale;
                Qb[((size_t)b * TDIM + t) * ADIM + (wc * 64 + j * 16 + ln15)] = f2bf(qv);
            }
        }
    } else {
        // ================= kv_proj role =================
        const int kv_id = bid / 3;                       // 0..255
        if (tid < 256) {
            short* sA  = (short*)smem;                   // [32*40]
            short* sWk = (short*)(smem + 2560);          // [2][128*40]
            const int r0 = kv_id * 32;
            const int b = r0 >> 10, sbase = r0 & 1023;
            const int kv = wave >> 1;        // 0 = K, 1 = V
            const int mh = wave & 1;
            const int m  = mh * 16 + ln15;

            f4v acc[8];
            #pragma unroll
            for (int j = 0; j < 8; ++j) acc[j] = (f4v)0.0f;

            const int srow = tid >> 3;          // 0..31
            const int sk4  = (tid & 7) * 4;     // 0,4,..,28

            for (int kc = 0; kc < DDIM / 32; ++kc) {
                __syncthreads();
                {   // stage sem tile [32][32] fp32 -> bf16
                    float4 f = *(const float4*)&sem[(size_t)(r0 + srow) * DDIM + kc * 32 + sk4];
                    uint2 pk;
                    pk.x = (unsigned short)f2bf(f.x) | ((unsigned)(unsigned short)f2bf(f.y) << 16);
                    pk.y = (unsigned short)f2bf(f.z) | ((unsigned)(unsigned short)f2bf(f.w) << 16);
                    *(uint2*)&sA[srow * 40 + sk4] = pk;
                }
                #pragma unroll
                for (int i = 0; i < 2; ++i) {   // stage Wk/Wv chunks [128][32]
                    int idx8 = i * 256 + tid;
                    int n = idx8 >> 2, k8 = (idx8 & 3) * 8;
                    *(s8v*)&sWk[n * 40 + k8] = *(const s8v*)&WkT[(size_t)n * 768 + kc * 32 + k8];
                    *(s8v*)&sWk[5120 + n * 40 + k8] = *(const s8v*)&WvT[(size_t)n * 768 + kc * 32 + k8];
                }
                __syncthreads();
                s8v a = *(const s8v*)&sA[m * 40 + kq];
                #pragma unroll
                for (int j = 0; j < 8; ++j) {
                    s8v bb = *(const s8v*)&sWk[kv * 5120 + (j * 16 + ln15) * 40 + kq];
                    acc[j] = mfma16(a, bb, acc[j]);
                }
            }
            const int s_in_b = sbase + mh * 16 + q * 4;
            if (kv == 0) {
                #pragma unroll
                for (int j = 0; j < 8; ++j) {
                    int col = j * 16 + ln15;
                    float bias = bk[col];
                    #pragma unroll
                    for (int r = 0; r < 4; ++r)
                        Kb[((size_t)b * SDIM + s_in_b + r) * ADIM + col] = f2bf(acc[j][r] + bias);
                }
            } else {
                #pragma unroll
                for (int j = 0; j < 8; ++j) {
                    int col = j * 16 + ln15;
                    float bias = bv[col];
                    uint2 pk;
                    pk.x = (unsigned short)f2bf(acc[j][0] + bias) | ((unsigned)(unsigned short)f2bf(acc[j][1] + bias) << 16);
                    pk.y = (unsigned short)f2bf(acc[j][2] + bias) | ((unsigned)(unsigned short)f2bf(acc[j][3] + bias) << 16);
                    *(uint2*)&Vb[((size_t)b * ADIM + col) * SDIM + s_in_b] = pk;
                }
            }
        } else {
            // idle upper waves: match the active threads' barrier sequence
            for (int kc = 0; kc < DDIM / 32; ++kc) { __syncthreads(); __syncthreads(); }
        }
    }
}

// ---------------------------------------------------------------------------
// attn: flash-style, no max subtraction. Q frags in registers (no sQ).
// XOR-swizzled unpadded LDS tiles; double-buffered K/V with register
// prefetch; row-sums via MFMA-with-ones. 512 blocks, 2/CU, LDS 72 KB.
// ---------------------------------------------------------------------------
__global__ __launch_bounds__(256) void attn(
    const short* __restrict__ Qb, const short* __restrict__ Kb,
    const short* __restrict__ Vb, short* __restrict__ Cx)
{
    __shared__ __align__(16) short sK [2][64 * 128];  // [s][a]  kb ^= row&15
    __shared__ __align__(16) short sVT[2][128 * 64];  // [a][s]  kb ^= row&7
    __shared__ __align__(16) short sP [64 * 64];      // [t][s]  kb ^= row&7 (wave-private rows)
    const int tid = threadIdx.x, lane = tid & 63, wave = tid >> 6;
    const int ln15 = lane & 15, q = lane >> 4, kq = q * 8;
    const int b = blockIdx.x >> 6;
    const int t0 = (blockIdx.x & 63) * 64;
    const int m = wave * 16 + ln15;

    const int krow = tid >> 4, kkb = tid & 15;   // K staging: row = i*16+krow
    const int varow = tid >> 3, vkb = tid & 7;   // VT staging: row = i*32+varow

    s8v qf[4];
    {
        const short* qp = Qb + ((size_t)b * TDIM + t0 + m) * ADIM + kq;
        #pragma unroll
        for (int kc = 0; kc < 4; ++kc) qf[kc] = *(const s8v*)(qp + kc * 32);
    }
    s8v ones;
    #pragma unroll
    for (int j = 0; j < 8; ++j) ones[j] = (short)0x3F80;  // bf16 1.0

    f4v accO[8]; f4v accL = (f4v)0.0f;
    #pragma unroll
    for (int j = 0; j < 8; ++j) accO[j] = (f4v)0.0f;

    const short* Kbase = Kb + (size_t)b * SDIM * ADIM;
    const short* Vbase = Vb + (size_t)b * ADIM * SDIM;
    s8v rk[4], rv[4];

    #pragma unroll
    for (int i = 0; i < 4; ++i) {       // prologue: load + store chunk 0
        rk[i] = *(const s8v*)(Kbase + (size_t)(i * 16 + krow) * ADIM + kkb * 8);
        rv[i] = *(const s8v*)(Vbase + (size_t)(i * 32 + varow) * SDIM + vkb * 8);
    }
    #pragma unroll
    for (int i = 0; i < 4; ++i) {
        int r = i * 16 + krow;
        *(s8v*)&sK[0][r * 128 + ((kkb ^ (r & 15)) * 8)] = rk[i];
        int a = i * 32 + varow;
        *(s8v*)&sVT[0][a * 64 + ((vkb ^ (a & 7)) * 8)] = rv[i];
    }
    __syncthreads();

    for (int sc = 0; sc < SDIM / 64; ++sc) {
        const int cur = sc & 1;
        if (sc < 15) {                  // prefetch next chunk into registers
            const int s0n = (sc + 1) * 64;
            #pragma unroll
            for (int i = 0; i < 4; ++i) {
                rk[i] = *(const s8v*)(Kbase + (size_t)(s0n + i * 16 + krow) * ADIM + kkb * 8);
                rv[i] = *(const s8v*)(Vbase + (size_t)(i * 32 + varow) * SDIM + s0n + vkb * 8);
            }
        }
        // QK^T -> exp -> sP (wave-private rows, no block barrier needed)
        #pragma unroll
        for (int j = 0; j < 4; ++j) {
            f4v sacc = (f4v)0.0f;
            const int row = j * 16 + ln15;
            #pragma unroll
            for (int kc = 0; kc < 4; ++kc) {
                s8v bb = *(const s8v*)&sK[cur][row * 128 + (((kc * 4 + q) ^ (row & 15)) * 8)];
                sacc = mfma16(qf[kc], bb, sacc);
            }
            #pragma unroll
            for (int r = 0; r < 4; ++r) {
                float ev = __expf(sacc[r]);
                int prow = wave * 16 + q * 4 + r;
                int pcol = j * 16 + ln15;
                sP[prow * 64 + (((pcol >> 3) ^ (prow & 7)) * 8) + (pcol & 7)] = f2bf(ev);
            }
        }
        // PV + row-sum via MFMA-with-ones
        #pragma unroll
        for (int kc = 0; kc < 2; ++kc) {
            s8v pa = *(const s8v*)&sP[m * 64 + (((kc * 4 + q) ^ (m & 7)) * 8)];
            accL = mfma16(pa, ones, accL);
            #pragma unroll
            for (int j = 0; j < 8; ++j) {
                int a = j * 16 + ln15;
                s8v bb = *(const s8v*)&sVT[cur][a * 64 + (((kc * 4 + q) ^ (a & 7)) * 8)];
                accO[j] = mfma16(pa, bb, accO[j]);
            }
        }
        if (sc < 15) {                  // write prefetched chunk to other buffer
            #pragma unroll
            for (int i = 0; i < 4; ++i) {
                int r = i * 16 + krow;
                *(s8v*)&sK[cur ^ 1][r * 128 + ((kkb ^ (r & 15)) * 8)] = rk[i];
                int a = i * 32 + varow;
                *(s8v*)&sVT[cur ^ 1][a * 64 + ((vkb ^ (a & 7)) * 8)] = rv[i];
            }
        }
        __syncthreads();
    }
    #pragma unroll
    for (int r = 0; r < 4; ++r) {
        float rinv = 1.0f / accL[r];
        int t = t0 + wave * 16 + q * 4 + r;
        #pragma unroll
        for (int j = 0; j < 8; ++j) {
            int col = j * 16 + ln15;
            Cx[((size_t)b * TDIM + t) * ADIM + col] = f2bf(accO[j][r] * rinv);
        }
    }
}

// ---------------------------------------------------------------------------
// out_proj: delta = ctx @ Wo + bo, written transposed [B][C][T] coalesced
// ---------------------------------------------------------------------------
__global__ __launch_bounds__(256) void out_proj(
    const short* __restrict__ Cx, const short* __restrict__ WoT,
    const float* __restrict__ bo, float* __restrict__ out)
{
    __shared__ __align__(16) short sCtx[64 * 136];  // [t][a128 + pad8]
    __shared__ __align__(16) char  buf[128 * 136 * 2];
    short* sWoT = (short*)buf;                      // [c128][k128 + pad8]
    float* outT = (float*)buf;                      // [c128][t64 + pad4]
    const int tid = threadIdx.x, lane = tid & 63, wave = tid >> 6;
    const int ln15 = lane & 15, q = lane >> 4, kq = q * 8;
    const int b = blockIdx.x >> 8;
    const int rem = blockIdx.x & 255;
    const int t0 = (rem & 63) * 64;
    const int c0 = (rem >> 6) * 128;

    #pragma unroll
    for (int i = 0; i < 4; ++i) {
        int idx8 = i * 256 + tid;
        int row = idx8 >> 4, a8 = (idx8 & 15) * 8;
        *(s8v*)&sCtx[row * 136 + a8] = *(const s8v*)&Cx[((size_t)b * TDIM + t0 + row) * ADIM + a8];
    }
    #pragma unroll
    for (int i = 0; i < 8; ++i) {
        int idx8 = i * 256 + tid;
        int n = idx8 >> 4, k8 = (idx8 & 15) * 8;
        *(s8v*)&sWoT[n * 136 + k8] = *(const s8v*)&WoT[(size_t)(c0 + n) * ADIM + k8];
    }
    __syncthreads();
    f4v acc[8];
    #pragma unroll
    for (int j = 0; j < 8; ++j) acc[j] = (f4v)0.0f;
    const int m = wave * 16 + ln15;
    #pragma unroll
    for (int kc = 0; kc < 4; ++kc) {
        s8v a = *(const s8v*)&sCtx[m * 136 + kc * 32 + kq];
        #pragma unroll
        for (int j = 0; j < 8; ++j) {
            s8v bb = *(const s8v*)&sWoT[(j * 16 + ln15) * 136 + kc * 32 + kq];
            acc[j] = mfma16(a, bb, acc[j]);
        }
    }
    __syncthreads();    // reuse buf as outT
    #pragma unroll
    for (int j = 0; j < 8; ++j) {
        int cl = j * 16 + ln15;
        float bias = bo[c0 + cl];
        #pragma unroll
        for (int r = 0; r < 4; ++r) {
            int tl = wave * 16 + q * 4 + r;
            outT[cl * 68 + tl] = acc[j][r] + bias;
        }
    }
    __syncthreads();
    #pragma unroll
    for (int i = 0; i < 8; ++i) {
        int idx4 = i * 256 + tid;
        int c = idx4 >> 4, t4 = (idx4 & 15) * 4;
        float4 v = *(const float4*)&outT[c * 68 + t4];
        *(float4*)&out[((size_t)b * CDIM + c0 + c) * TDIM + t0 + t4] = v;
    }
}

// ---------------------------------------------------------------------------
extern "C" void kernel_launch(void* const* d_in, const int* in_sizes, int n_in,
                              void* d_out, int out_size, void* d_ws, size_t ws_size,
                              hipStream_t stream) {
    const float* x   = (const float*)d_in[0];
    const float* sem = (const float*)d_in[1];
    const float* lnw = (const float*)d_in[2];
    const float* lnb = (const float*)d_in[3];
    const float* Wq  = (const float*)d_in[4];
    const float* bq  = (const float*)d_in[5];
    const float* Wk  = (const float*)d_in[6];
    const float* bk  = (const float*)d_in[7];
    const float* Wv  = (const float*)d_in[8];
    const float* bv  = (const float*)d_in[9];
    const float* Wo  = (const float*)d_in[10];
    const float* bo  = (const float*)d_in[11];
    float* out = (float*)d_out;

    short* ws  = (short*)d_ws;
    short* Qb  = ws;                                    // [B][T][A]  bf16
    short* Kb  = Qb  + (size_t)BATCH * TDIM * ADIM;     // [B][S][A]
    short* Vb  = Kb  + (size_t)BATCH * SDIM * ADIM;     // [B][A][S]  (transposed)
    short* Cx  = Vb  + (size_t)BATCH * SDIM * ADIM;     // [B][T][A]
    short* WqT = Cx  + (size_t)BATCH * TDIM * ADIM;     // [8][128][64] LDS image (ln_w folded)
    short* WkT = WqT + 128 * 512;                       // [128][768]
    short* WvT = WkT + 128 * 768;                       // [128][768]
    short* WoT = WvT + 128 * 768;                       // [512][128]
    float* uq  = (float*)(WoT + 512 * 128);             // [128]
    float* vq  = uq + 128;                              // [128]

    hipMemsetAsync(uq, 0, 256 * sizeof(float), stream); // zero uq+vq
    hipLaunchKernelGGL(prep, dim3(512), dim3(256), 0, stream,
                       Wq, Wk, Wv, Wo, lnw, lnb, WqT, WkT, WvT, WoT, uq, vq);
    hipLaunchKernelGGL(mid,  dim3(768), dim3(512), 0, stream,
                       x, WqT, uq, vq, bq, Qb, sem, WkT, bk, WvT, bv, Kb, Vb);
    hipLaunchKernelGGL(attn, dim3(512), dim3(256), 0, stream, Qb, Kb, Vb, Cx);
    hipLaunchKernelGGL(out_proj, dim3(2048), dim3(256), 0, stream, Cx, WoT, bo, out);
}